// Round 6
// baseline (376.297 us; speedup 1.0000x reference)
//
#include <hip/hip_runtime.h>
#include <hip/hip_bf16.h>
#include <cmath>

#define N_SPH 7
#define N_RAD 6
#define NC (N_SPH * N_RAD)   // 42
#define INV_CUTOFF 0.2f

typedef float f2 __attribute__((ext_vector_type(2)));
typedef float f4 __attribute__((ext_vector_type(4)));
typedef _Float16 h8 __attribute__((ext_vector_type(8)));

// Compile-time m_c = round(z_c / (pi/2)), l-major. Verified against z-values;
// max |delta| = 0.796 (element l=6,j=5). Host computes delta = z - m*pi/2
// consistently, so the identity sin(m*th+u) holds for any m.
static constexpr int M_TAB[NC] = {
    2,  4,  6,  8,  10, 12,   // l=0 (z = (j+1)*pi exactly -> delta = 0)
    3,  5,  7,  9,  11, 13,   // l=1
    4,  6,  8,  10, 12, 14,   // l=2
    4,  7,  9,  11, 13, 15,   // l=3
    5,  7,  10, 12, 14, 16,   // l=4
    6,  8,  10, 13, 15, 17,   // l=5
    7,  9,  11, 13, 15, 18};  // l=6

struct BesselConsts {
    float freq[NC];      // z_{l,j}, l-major
    float norm[NC];      // sqrt(2)/|j_{l+1}(z_{l,j})|
    float deltaf[NC];    // z - m*pi/2 (f32)
    float ycoef[N_SPH];  // sqrt((2l+1)/4pi)
    double deltad[NC];   // z - m*pi/2 (f64, for the 4 critical elements)
};

// ---------------- host-side precompute (graph-capture time only) ----------
static double h_sph_jn(double t, int l) {
    double j0 = sin(t) / t;
    if (l == 0) return j0;
    double j1 = sin(t) / (t * t) - cos(t) / t;
    for (int i = 2; i <= l; i++) {
        double j2 = (2.0 * i - 1.0) / t * j1 - j0;
        j0 = j1; j1 = j2;
    }
    return j1;
}

static void compute_consts(BesselConsts* bc) {
    const int n = N_SPH, k = N_RAD, nz = N_RAD + N_SPH - 1;  // 12
    const double PI = 3.14159265358979323846;
    const double PI_2 = 1.57079632679489661923;
    double zeros[N_SPH][12];
    for (int i = 0; i < nz; i++) zeros[0][i] = (i + 1) * PI;
    for (int l = 1; l < n; l++) {
        for (int i = 0; i < nz - l; i++) {
            double a = zeros[l - 1][i], b = zeros[l - 1][i + 1];
            double fa = h_sph_jn(a, l);
            for (int it = 0; it < 80; it++) {
                double m = 0.5 * (a + b);
                double fm = h_sph_jn(m, l);
                if (fa * fm <= 0.0) { b = m; } else { a = m; fa = fm; }
            }
            zeros[l][i] = 0.5 * (a + b);
        }
    }
    for (int l = 0; l < n; l++)
        for (int j = 0; j < k; j++) {
            const int c = l * k + j;
            bc->freq[c] = (float)zeros[l][j];
            bc->norm[c] =
                (float)(sqrt(2.0) / fabs(h_sph_jn(zeros[l][j], l + 1)));
            double dd = zeros[l][j] - (double)M_TAB[c] * PI_2;
            bc->deltad[c] = dd;
            bc->deltaf[c] = (float)dd;
        }
    for (int l = 0; l < n; l++)
        bc->ycoef[l] = (float)sqrt((2.0 * l + 1.0) / (4.0 * PI));
}

// ---------------- per-element device helpers ------------------------------
// f32 path. Seed sin/cos of m*th comes f32-cast from the f64 chain
// (delta-s ~ 6e-8), so output error ~ eps * amplification * norm * env:
// worst demoted element (6,2) ~ 0.013 abs -- inside the 0.25 budget.
template <int L, int C_>
__device__ __forceinline__ void elem32(float x, float env, float Sf, float Cf,
                                       const float* yP, _Float16* strow,
                                       const BesselConsts& bc) {
    float tt = x * bc.freq[C_];
    float u = x * bc.deltaf[C_];
    float v = u * u;
    // |u| <= 0.80: sin to u^7 (err <= 3.5e-7), cos to u^8 (err <= 2.8e-8)
    float su = u * fmaf(v, fmaf(v, fmaf(v, -1.9841270e-4f, 8.3333333e-3f),
                                 -1.6666667e-1f), 1.0f);
    float cu = fmaf(v, fmaf(v, fmaf(v, fmaf(v, 2.4801587e-5f, -1.3888889e-3f),
                                    4.1666667e-2f), -0.5f), 1.0f);
    float s = fmaf(Sf, cu, Cf * su);     // sin(m*th + u)
    float co = fmaf(Cf, cu, -(Sf * su)); // cos(m*th + u)
    float r = __builtin_amdgcn_rcpf(tt);
    r = r * fmaf(-tt, r, 2.0f);          // Newton -> ~0.5 ulp
    float jv;
    float j0 = s * r;
    if constexpr (L == 0) {
        jv = j0;
    } else {
        float j1 = fmaf(s, r, -co) * r;
#pragma unroll
        for (int i = 2; i <= L; ++i) {
            float j2 = fmaf((2.0f * i - 1.0f) * r, j1, -j0);
            j0 = j1; j1 = j2;
        }
        jv = j1;
    }
    strow[C_] = (_Float16)(yP[L] * (env * bc.norm[C_] * jv));
}

// f64 path: only elements {(4,0),(5,0),(6,0),(6,1)} where upward-recurrence
// amplification (~1e3-1e4 at small t) would push f32 error past ~0.05 abs.
template <int L, int C_>
__device__ __forceinline__ void elem64(float x, double xd, float env,
                                       double Sd, double Cd, const float* yP,
                                       _Float16* strow,
                                       const BesselConsts& bc) {
    float tt = x * bc.freq[C_];
    double u = xd * bc.deltad[C_];
    double v = u * u;
    double su = u * fma(v, fma(v, fma(v, fma(v, fma(v, -1.0 / 39916800.0,
                     1.0 / 362880.0), -1.0 / 5040.0), 1.0 / 120.0),
                     -1.0 / 6.0), 1.0);
    double cu = fma(v, fma(v, fma(v, fma(v, fma(v, fma(v, 1.0 / 479001600.0,
                     -1.0 / 3628800.0), 1.0 / 40320.0), -1.0 / 720.0),
                     1.0 / 24.0), -0.5), 1.0);
    double s = fma(Sd, cu, Cd * su);
    double co = fma(Cd, cu, -(Sd * su));
    double td = (double)tt;
    float rf = __builtin_amdgcn_rcpf(tt);
    double r = (double)rf;
    r = r * fma(-td, r, 2.0);            // Newton in f64: ~1e-14 rel
    double j0 = s * r;
    double j1 = fma(s, r, -co) * r;      // L>=4 always here
#pragma unroll
    for (int i = 2; i <= L; ++i) {
        double j2 = fma((2.0 * i - 1.0) * r, j1, -j0);
        j0 = j1; j1 = j2;
    }
    strow[C_] = (_Float16)(yP[L] * (env * bc.norm[C_] * (float)j1));
}

// ---------------- fused row kernel: one thread per triplet row ------------
// R5 post-mortem: kernel was LATENCY-bound (~160 us vs ~40 us issue floor) at
// 12 waves/CU (43 KB f32 LDS stage -> 3 blocks/CU). This version:
//  - f16 LDS stage (21.5 KB): quantization <= 7e-3 abs, doubles LDS headroom
//  - __launch_bounds__(256,5): 5 blocks/CU -> 20 waves/CU
//  - f64 only for seed chain + 4 critical elements (f64 ops ~530 -> ~170)
//  - small-angle polys trimmed to the |u|<=0.80 domain
__global__ __launch_bounds__(256, 5) void fused_row_kernel(
    const float* __restrict__ dist, const float* __restrict__ angle,
    const int* __restrict__ idx, float* __restrict__ out, int T_,
    BesselConsts bc) {
    __shared__ __align__(16) _Float16 stage[256 * NC];  // 21.5 KB
    const int tix = threadIdx.x;
    const int t0 = blockIdx.x * 256;
    const int t = t0 + tix;
    const bool valid = t < T_;

    float x = 0.5f, cth = 0.0f;
    if (valid) {
        x = dist[idx[t]] * INV_CUTOFF;  // L2-resident random gather (2 MB)
        cth = cosf(angle[t]);
    }
    // p=5 envelope: 1/x + x^5*(-21 + x*(35 - 15x))
    float xp = x * x * x * x * x;
    float env = 1.0f / x + xp * (-21.0f + x * (35.0f - 15.0f * x));
    // Legendre P_l(cos th) -> yP[l] (compile-time indexed -> registers)
    float P[N_SPH];
    P[0] = 1.0f;
    P[1] = cth;
#pragma unroll
    for (int l = 2; l < N_SPH; ++l)
        P[l] = ((2 * l - 1) * cth * P[l - 1] - (l - 1) * P[l - 2]) *
               (1.0f / (float)l);
    float yP[N_SPH];
#pragma unroll
    for (int l = 0; l < N_SPH; ++l) yP[l] = bc.ycoef[l] * P[l];

    // f64 sin/cos of th = x*pi/2 over [0, pi/2]: single-interval Taylor,
    // error ~4e-11 -- no range reduction. This chain is the accuracy
    // backbone: f32 elements cast its S,C (seed err ~6e-8).
    double xd = (double)x;
    double th = xd * 1.57079632679489661923;
    double w = th * th;
    double s1 = th * fma(w, fma(w, fma(w, fma(w, fma(w, fma(w,
                     1.0 / 6227020800.0, -1.0 / 39916800.0), 1.0 / 362880.0),
                     -1.0 / 5040.0), 1.0 / 120.0), -1.0 / 6.0), 1.0);
    double c1 = fma(w, fma(w, fma(w, fma(w, fma(w, fma(w, fma(w,
                     -1.0 / 87178291200.0, 1.0 / 479001600.0),
                     -1.0 / 3628800.0), 1.0 / 40320.0), -1.0 / 720.0),
                     1.0 / 24.0), -0.5), 1.0);
    double S = s1, C = c1;  // (sin,cos) of m*th, currently m=1

    _Float16* strow = &stage[tix * NC];

#define STEP() do { double Sn = fma(S, c1, C * s1); \
                    C = fma(C, c1, -(S * s1)); S = Sn; } while (0)
#define E32(L_, C_) do { float Sf = (float)S, Cf = (float)C; \
                         elem32<L_, C_>(x, env, Sf, Cf, yP, strow, bc); } while (0)
#define E64(L_, C_) elem64<L_, C_>(x, xd, env, S, C, yP, strow, bc)

    STEP();  E32(0, 0);                                      // m=2
    STEP();  E32(1, 6);                                      // m=3
    STEP();  E32(0, 1);  E32(2, 12); E32(3, 18);             // m=4
    STEP();  E32(1, 7);  E64(4, 24);                         // m=5
    STEP();  E32(0, 2);  E32(2, 13); E64(5, 30);             // m=6
    STEP();  E32(1, 8);  E32(3, 19); E32(4, 25); E64(6, 36); // m=7
    STEP();  E32(0, 3);  E32(2, 14); E32(5, 31);             // m=8
    STEP();  E32(1, 9);  E32(3, 20); E64(6, 37);             // m=9
    STEP();  E32(0, 4);  E32(2, 15); E32(4, 26); E32(5, 32); // m=10
    STEP();  E32(1, 10); E32(3, 21); E32(6, 38);             // m=11
    STEP();  E32(0, 5);  E32(2, 16); E32(4, 27);             // m=12
    STEP();  E32(1, 11); E32(3, 22); E32(5, 33); E32(6, 39); // m=13
    STEP();  E32(2, 17); E32(4, 28);                         // m=14
    STEP();  E32(3, 23); E32(5, 34); E32(6, 40);             // m=15
    STEP();  E32(4, 29);                                     // m=16
    STEP();  E32(5, 35);                                     // m=17
    STEP();  E32(6, 41);                                     // m=18
#undef STEP
#undef E32
#undef E64

    __syncthreads();

    // coalesced copy-out: read 8 f16 (b128), cvt, 2x NT f4 stores.
    // Full block: 256*42 = 10752 f16 -> 1344 b128 reads (5.25/thread).
    const int rows = min(256, T_ - t0);
    const int nelem = rows * NC;
    const int n8 = nelem >> 3;
    const size_t base = (size_t)t0 * NC;
#pragma unroll
    for (int it = 0; it < 6; ++it) {
        int i = it * 256 + tix;
        if (i < n8) {
            h8 hv = *reinterpret_cast<const h8*>(&stage[8 * i]);
            f4 lo = {(float)hv[0], (float)hv[1], (float)hv[2], (float)hv[3]};
            f4 hi = {(float)hv[4], (float)hv[5], (float)hv[6], (float)hv[7]};
            __builtin_nontemporal_store(
                lo, reinterpret_cast<f4*>(out + base + 8 * (size_t)i));
            __builtin_nontemporal_store(
                hi, reinterpret_cast<f4*>(out + base + 8 * (size_t)i + 4));
        }
    }
    for (int i = n8 * 8 + tix; i < nelem; i += 256)
        __builtin_nontemporal_store((float)stage[i], out + base + i);
}

extern "C" void kernel_launch(void* const* d_in, const int* in_sizes, int n_in,
                              void* d_out, int out_size, void* d_ws,
                              size_t ws_size, hipStream_t stream) {
    const float* dist = (const float*)d_in[0];
    const float* angle = (const float*)d_in[1];
    const int* idx = (const int*)d_in[2];
    float* out = (float*)d_out;

    int E_ = in_sizes[0];
    int T_ = in_sizes[1];
    (void)E_; (void)d_ws; (void)ws_size;

    BesselConsts bc;
    compute_consts(&bc);

    fused_row_kernel<<<(T_ + 255) / 256, 256, 0, stream>>>(dist, angle, idx,
                                                           out, T_, bc);
}